// Round 7
// baseline (126.667 us; speedup 1.0000x reference)
//
#include <hip/hip_runtime.h>

using f32x4  = __attribute__((ext_vector_type(4))) float;
using f32x16 = __attribute__((ext_vector_type(16))) float;
using bf16x8 = __attribute__((ext_vector_type(8))) __bf16;

static constexpr int DD = 512;
static constexpr int NTOK = 4096;  // B*V

__device__ __forceinline__ float bf2f(unsigned short u) {
  unsigned int v = ((unsigned int)u) << 16;
  return __builtin_bit_cast(float, v);
}
__device__ __forceinline__ float bflo(unsigned int u) {
  return __builtin_bit_cast(float, u << 16);
}
__device__ __forceinline__ float bfhi(unsigned int u) {
  return __builtin_bit_cast(float, u & 0xffff0000u);
}
__device__ __forceinline__ unsigned short f2bf(float f) {
  unsigned int u = __builtin_bit_cast(unsigned int, f);
  unsigned int r = u + 0x7fffu + ((u >> 16) & 1u);
  return (unsigned short)(r >> 16);
}
__device__ __forceinline__ float lrelu(float v) { return v >= 0.f ? v : 0.2f * v; }

// 16-wide fragment-panel (for gemm_ac/fusion, 16x16x32 MFMA):
//   off = (tile16*KS + ks)*512 + ((k>>3)&3)*128 + (row&15)*8 + (k&7)
// 32-wide fragment-panel (relation, 32x32x16 MFMA), lane = ((k>>3)&1)*32+row31:
//   off = frag*512 + ((k>>3)&1)*256 + (row&31)*8 + (k&7)

// ---- k_prep: all layout transforms + BN accumulator zeroing, one dispatch ----
__global__ __launch_bounds__(256) void k_prep(const float* __restrict__ F,
                                              const float* __restrict__ W1,
                                              const float* __restrict__ W2,
                                              const float* __restrict__ W3,
                                              const float* __restrict__ Wf,
                                              unsigned short* __restrict__ XP,
                                              unsigned short* __restrict__ W1P,
                                              unsigned short* __restrict__ W2P,
                                              unsigned short* __restrict__ W3P,
                                              unsigned short* __restrict__ WfP,
                                              float* __restrict__ sums) {
  const int bid = blockIdx.x, tid = threadIdx.x;
  if (bid < 8192) {                       // F -> XP (16-panel layout, ks 0..15 of 32)
    int idx = (bid << 8) + tid;           // 4096*512
    int t = idx >> 9, c = idx & 511;
    XP[((t >> 4) * 32 + (c >> 5)) * 512 + ((c >> 3) & 3) * 128 + (t & 15) * 8 + (c & 7)] = f2bf(F[idx]);
  } else if (bid < 10240) {               // W1 (1024,512) -> W1P 16-frag order (K=512, N=1024 combined)
    int idx = ((bid - 8192) << 8) + tid;  // 512*1024
    int k = idx >> 10, n = idx & 1023;
    float v = W1[(n < 512 ? k : 512 + k) * 512 + (n & 511)];
    W1P[((n >> 4) * 16 + (k >> 5)) * 512 + ((k >> 3) & 3) * 128 + (n & 15) * 8 + (k & 7)] = f2bf(v);
  } else if (bid < 11264) {               // W2 (512,512) -> W2P 32-frag fg-major
    int idx = ((bid - 10240) << 8) + tid;
    int k = idx >> 9, n = idx & 511;
    int off = (((n >> 6) * 32 + (k >> 4)) * 2 + ((n >> 5) & 1)) * 512 +
              ((k >> 3) & 1) * 256 + (n & 31) * 8 + (k & 7);
    W2P[off] = f2bf(W2[idx]);
  } else if (bid < 12288) {               // W3 -> 32-frag fg-major
    int idx = ((bid - 11264) << 8) + tid;
    int k = idx >> 9, n = idx & 511;
    int off = (((n >> 6) * 32 + (k >> 4)) * 2 + ((n >> 5) & 1)) * 512 +
              ((k >> 3) & 1) * 256 + (n & 31) * 8 + (k & 7);
    W3P[off] = f2bf(W3[idx]);
  } else if (bid < 14336) {               // Wf (1024,512) -> WfP 16-frag (K=1024)
    int idx = ((bid - 12288) << 8) + tid;
    int k = idx >> 9, n = idx & 511;
    WfP[((n >> 4) * 32 + (k >> 5)) * 512 + ((k >> 3) & 3) * 128 + (n & 15) * 8 + (k & 7)] = f2bf(Wf[idx]);
  } else {                                // zero sums+sumsq (1024 floats)
    reinterpret_cast<float4*>(sums)[tid] = float4{0.f, 0.f, 0.f, 0.f};
  }
}

// ---- GEMM1: ACP = [F@W1a | F@W1b] in 16-panel layout. grid (64,4), 512 thr ----
__global__ __launch_bounds__(512) void k_gemm_ac(const unsigned short* __restrict__ XP,
                                                 const unsigned short* __restrict__ W1P,
                                                 unsigned short* __restrict__ ACP) {
  const int tid = threadIdx.x, lane = tid & 63, wid = tid >> 6;
  const int wm = wid >> 2, wn = wid & 3;
  const int l15 = lane & 15;
  const int bx = blockIdx.x, by = blockIdx.y;

  f32x4 acc[2][4];
#pragma unroll
  for (int mt = 0; mt < 2; ++mt)
#pragma unroll
    for (int nt = 0; nt < 4; ++nt) acc[mt][nt] = f32x4{0.f, 0.f, 0.f, 0.f};

  bf16x8 ca[2], cb[4], na[2], nb[4];
  auto ldA = [&](bf16x8 (&d)[2], int ks) {
#pragma unroll
    for (int mt = 0; mt < 2; ++mt)
      d[mt] = *reinterpret_cast<const bf16x8*>(XP + (((bx * 4 + wm * 2 + mt) * 32 + ks) << 9) + lane * 8);
  };
  auto ldB = [&](bf16x8 (&d)[4], int ks) {
#pragma unroll
    for (int nt = 0; nt < 4; ++nt)
      d[nt] = *reinterpret_cast<const bf16x8*>(W1P + ((((by * 16 + wn * 4 + nt) * 16) + ks) << 9) + lane * 8);
  };

  ldA(ca, 0); ldB(cb, 0);
  for (int ks = 0; ks < 16; ++ks) {
    int kn = (ks + 1) & 15;
    ldA(na, kn); ldB(nb, kn);
    __builtin_amdgcn_s_setprio(1);
#pragma unroll
    for (int mt = 0; mt < 2; ++mt)
#pragma unroll
      for (int nt = 0; nt < 4; ++nt)
        acc[mt][nt] = __builtin_amdgcn_mfma_f32_16x16x32_bf16(ca[mt], cb[nt], acc[mt][nt], 0, 0, 0);
    __builtin_amdgcn_s_setprio(0);
#pragma unroll
    for (int q = 0; q < 2; ++q) ca[q] = na[q];
#pragma unroll
    for (int q = 0; q < 4; ++q) cb[q] = nb[q];
  }
#pragma unroll
  for (int mt = 0; mt < 2; ++mt)
#pragma unroll
    for (int nt = 0; nt < 4; ++nt) {
      int col = by * 256 + wn * 64 + nt * 16 + l15;
      int panel = bx * 4 + wm * 2 + mt;
#pragma unroll
      for (int r = 0; r < 4; ++r) {
        int rowi = (lane >> 4) * 4 + r;
        ACP[(panel * 32 + (col >> 5)) * 512 + ((col >> 3) & 3) * 128 + rowi * 8 + (col & 7)] = f2bf(acc[mt][nt][r]);
      }
    }
}

// ---- relation: block = (b, half) -> 8 tokens x 16 j = 128 relrows ----
// 32x32x16 MFMA. 1024 thr = 16 waves (4/SIMD), wave = fg(0..7; 64 feats) x rg(0..1; 64 relrows).
// Operand-swapped (W = A from global, h = B in LDS 32-frag panels).
// Both operands double-buffered with NAMED buffers (no runtime indexing).
__global__ __launch_bounds__(1024, 4) void k_relation(const unsigned short* __restrict__ ACP,
                                                      const unsigned short* __restrict__ W2P,
                                                      const unsigned short* __restrict__ W3P,
                                                      const float* __restrict__ b1,
                                                      const float* __restrict__ b2,
                                                      const float* __restrict__ b3,
                                                      unsigned short* __restrict__ XP) {
  __shared__ unsigned short lds[65536];  // 4 rtiles x 32 ks16 x 512 el = 128 KB
  char* ldsb = reinterpret_cast<char*>(lds);
  const int tid = threadIdx.x;
  const int b = blockIdx.x >> 1, half = blockIdx.x & 1;

  // ---- phase 0: h1 = lrelu(A_i + C_j + b1) -> LDS 32-frag panels ----
  // tid bits: [9:6]=rhigh, [5:3]=c8 base, [2:0]=rlow  (writes tile all 32 banks)
  {
    const int c8b = (tid >> 3) & 7;
    const int r = ((tid >> 6) << 3) | (tid & 7);   // relrow 0..127 = il*16 + j
    const int il = r >> 4, j = r & 15;
    const int rowA = half * 8 + il;
    const int rt = r >> 5, r31 = r & 31;
#pragma unroll
    for (int it = 0; it < 8; ++it) {
      const int c8 = c8b + it * 8;               // feat octet 0..63
      uint4 av = *reinterpret_cast<const uint4*>(ACP + ((b * 32 + (c8 >> 2)) << 9) + (c8 & 3) * 128 + rowA * 8);
      uint4 cv = *reinterpret_cast<const uint4*>(ACP + ((b * 32 + 16 + (c8 >> 2)) << 9) + (c8 & 3) * 128 + j * 8);
      float4 bv0 = *reinterpret_cast<const float4*>(b1 + c8 * 8);
      float4 bv1 = *reinterpret_cast<const float4*>(b1 + c8 * 8 + 4);
      unsigned int au[4] = {av.x, av.y, av.z, av.w};
      unsigned int cu[4] = {cv.x, cv.y, cv.z, cv.w};
      float bb[8] = {bv0.x, bv0.y, bv0.z, bv0.w, bv1.x, bv1.y, bv1.z, bv1.w};
      unsigned int ou[4];
#pragma unroll
      for (int q = 0; q < 4; ++q) {
        float v0 = lrelu(bflo(au[q]) + bflo(cu[q]) + bb[2 * q]);
        float v1 = lrelu(bfhi(au[q]) + bfhi(cu[q]) + bb[2 * q + 1]);
        ou[q] = ((unsigned int)f2bf(v1) << 16) | (unsigned int)f2bf(v0);
      }
      uint4 o; o.x = ou[0]; o.y = ou[1]; o.z = ou[2]; o.w = ou[3];
      *reinterpret_cast<uint4*>(ldsb + (rt * 32 + (c8 >> 1)) * 1024 + (c8 & 1) * 512 + r31 * 16) = o;
    }
  }
  __syncthreads();

  const int lane = tid & 63, wid = tid >> 6;
  const int r31 = lane & 31, h = lane >> 5;
  const int fg = wid >> 1;     // feature group: feats fg*64..+63 (2 m-tiles of 32)
  const int rg = wid & 1;      // relrow group: rtiles rg*2, rg*2+1

  const unsigned short* w2base = W2P + (fg << 15) + lane * 8;   // fg*32*2*512
  const unsigned short* w3base = W3P + (fg << 15) + lane * 8;
  const unsigned short* lrd = lds + (rg * 2) * 32 * 512 + lane * 8;

  f32x16 acc[2][2];
  bf16x8 aA[2], aB[2], bA[2], bB[2];

  auto ldA_ = [&](bf16x8 (&d)[2], const unsigned short* __restrict__ wb, int ks) {
    d[0] = *reinterpret_cast<const bf16x8*>(wb + ks * 1024);
    d[1] = *reinterpret_cast<const bf16x8*>(wb + ks * 1024 + 512);
  };
  auto ldB_ = [&](bf16x8 (&d)[2], int ks) {
    d[0] = *reinterpret_cast<const bf16x8*>(lrd + ks * 512);
    d[1] = *reinterpret_cast<const bf16x8*>(lrd + 32 * 512 + ks * 512);
  };

  auto layer = [&](const unsigned short* __restrict__ wb) {
#pragma unroll
    for (int mt = 0; mt < 2; ++mt)
#pragma unroll
      for (int nt = 0; nt < 2; ++nt)
#pragma unroll
        for (int e = 0; e < 16; ++e) acc[mt][nt][e] = 0.f;
    ldA_(aA, wb, 0); ldB_(bA, 0);
#pragma unroll 1
    for (int ks = 0; ks < 32; ks += 2) {
      ldA_(aB, wb, ks + 1); ldB_(bB, ks + 1);
      __builtin_amdgcn_s_setprio(1);
      acc[0][0] = __builtin_amdgcn_mfma_f32_32x32x16_bf16(aA[0], bA[0], acc[0][0], 0, 0, 0);
      acc[0][1] = __builtin_amdgcn_mfma_f32_32x32x16_bf16(aA[0], bA[1], acc[0][1], 0, 0, 0);
      acc[1][0] = __builtin_amdgcn_mfma_f32_32x32x16_bf16(aA[1], bA[0], acc[1][0], 0, 0, 0);
      acc[1][1] = __builtin_amdgcn_mfma_f32_32x32x16_bf16(aA[1], bA[1], acc[1][1], 0, 0, 0);
      __builtin_amdgcn_s_setprio(0);
      const int ksn = (ks + 2) & 31;
      ldA_(aA, wb, ksn); ldB_(bA, ksn);
      __builtin_amdgcn_s_setprio(1);
      acc[0][0] = __builtin_amdgcn_mfma_f32_32x32x16_bf16(aB[0], bB[0], acc[0][0], 0, 0, 0);
      acc[0][1] = __builtin_amdgcn_mfma_f32_32x32x16_bf16(aB[0], bB[1], acc[0][1], 0, 0, 0);
      acc[1][0] = __builtin_amdgcn_mfma_f32_32x32x16_bf16(aB[1], bB[0], acc[1][0], 0, 0, 0);
      acc[1][1] = __builtin_amdgcn_mfma_f32_32x32x16_bf16(aB[1], bB[1], acc[1][1], 0, 0, 0);
      __builtin_amdgcn_s_setprio(0);
    }
  };

  // store lrelu(acc + bias) into LDS h-panels (uint2 per 4-reg group)
  auto store_h = [&](const float* __restrict__ bias) {
#pragma unroll
    for (int mt = 0; mt < 2; ++mt)
#pragma unroll
      for (int g = 0; g < 4; ++g) {
        float4 bv = *reinterpret_cast<const float4*>(bias + fg * 64 + mt * 32 + g * 8 + h * 4);
        const int ks16 = fg * 4 + mt * 2 + (g >> 1);
        const int kh = g & 1;
#pragma unroll
        for (int nt = 0; nt < 2; ++nt) {
          unsigned int w0 = f2bf(lrelu(acc[mt][nt][4 * g + 0] + bv.x));
          unsigned int w1 = f2bf(lrelu(acc[mt][nt][4 * g + 1] + bv.y));
          unsigned int w2 = f2bf(lrelu(acc[mt][nt][4 * g + 2] + bv.z));
          unsigned int w3 = f2bf(lrelu(acc[mt][nt][4 * g + 3] + bv.w));
          uint2 val; val.x = (w1 << 16) | w0; val.y = (w3 << 16) | w2;
          *reinterpret_cast<uint2*>(ldsb + ((rg * 2 + nt) * 32 + ks16) * 1024 + kh * 512 + r31 * 16 + h * 8) = val;
        }
      }
  };

  layer(w2base);
  __syncthreads();           // all waves done reading h1
  store_h(b2);
  __syncthreads();
  layer(w3base);
  __syncthreads();           // all waves done reading h2
  store_h(b3);
  __syncthreads();

  // ---- j-sum: Msum[token][feat] = sum_j h3[il*16+j][feat], waves 0..7 ----
  if (wid < 8) {
    const int t = wid;             // token 0..7 within block
    const int o = lane;            // feat octet 0..63
    const char* base = ldsb + ((t >> 1) * 32 + (o >> 1)) * 1024 + (o & 1) * 512 + (t & 1) * 256;
    float s[8] = {0.f, 0.f, 0.f, 0.f, 0.f, 0.f, 0.f, 0.f};
#pragma unroll
    for (int it = 0; it < 16; ++it) {
      int j = (it + o) & 15;       // rotate to spread banks
      uint4 v = *reinterpret_cast<const uint4*>(base + j * 16);
      s[0] += bflo(v.x); s[1] += bfhi(v.x);
      s[2] += bflo(v.y); s[3] += bfhi(v.y);
      s[4] += bflo(v.z); s[5] += bfhi(v.z);
      s[6] += bflo(v.w); s[7] += bfhi(v.w);
    }
    uint4 o4;
    o4.x = ((unsigned int)f2bf(s[1]) << 16) | f2bf(s[0]);
    o4.y = ((unsigned int)f2bf(s[3]) << 16) | f2bf(s[2]);
    o4.z = ((unsigned int)f2bf(s[5]) << 16) | f2bf(s[4]);
    o4.w = ((unsigned int)f2bf(s[7]) << 16) | f2bf(s[6]);
    int tg15 = half * 8 + t;       // token within 16-token panel (panel = b)
    *reinterpret_cast<uint4*>(XP + ((b * 32 + 16 + (o >> 2)) << 9) + (o & 3) * 128 + tg15 * 8) = o4;
  }
}

// ---- fusion GEMM + BN partial stats. grid (64,4), 512 thr ----
__global__ __launch_bounds__(512) void k_fusion(const unsigned short* __restrict__ XP,
                                                const unsigned short* __restrict__ WfP,
                                                const float* __restrict__ bfv,
                                                float* __restrict__ y,
                                                float* __restrict__ sums,
                                                float* __restrict__ sumsq) {
  const int tid = threadIdx.x, lane = tid & 63, wid = tid >> 6;
  const int wm = wid >> 2, wn = wid & 3;
  const int l15 = lane & 15;
  const int bx = blockIdx.x, by = blockIdx.y;
  const int rowbase = bx * 64 + wm * 32;
  const int colbase = by * 128 + wn * 32;

  f32x4 acc[2][2];
#pragma unroll
  for (int mt = 0; mt < 2; ++mt)
#pragma unroll
    for (int nt = 0; nt < 2; ++nt) acc[mt][nt] = f32x4{0.f, 0.f, 0.f, 0.f};

  bf16x8 ca[2], cb[2], na[2], nb[2];
  auto ldA = [&](bf16x8 (&d)[2], int ks) {
#pragma unroll
    for (int mt = 0; mt < 2; ++mt)
      d[mt] = *reinterpret_cast<const bf16x8*>(XP + (((bx * 4 + wm * 2 + mt) * 32 + ks) << 9) + lane * 8);
  };
  auto ldB = [&](bf16x8 (&d)[2], int ks) {
#pragma unroll
    for (int nt = 0; nt < 2; ++nt)
      d[nt] = *reinterpret_cast<const bf16x8*>(WfP + (((by * 8 + wn * 2 + nt) * 32 + ks) << 9) + lane * 8);
  };

  ldA(ca, 0); ldB(cb, 0);
  for (int ks = 0; ks < 32; ++ks) {
    int kn = (ks + 1) & 31;
    ldA(na, kn); ldB(nb, kn);
    __builtin_amdgcn_s_setprio(1);
#pragma unroll
    for (int mt = 0; mt < 2; ++mt)
#pragma unroll
      for (int nt = 0; nt < 2; ++nt)
        acc[mt][nt] = __builtin_amdgcn_mfma_f32_16x16x32_bf16(ca[mt], cb[nt], acc[mt][nt], 0, 0, 0);
    __builtin_amdgcn_s_setprio(0);
#pragma unroll
    for (int q = 0; q < 2; ++q) { ca[q] = na[q]; cb[q] = nb[q]; }
  }

  float s[2] = {0.f, 0.f}, q2[2] = {0.f, 0.f};
#pragma unroll
  for (int nt = 0; nt < 2; ++nt) {
    int col = colbase + nt * 16 + l15;
    float bias = bfv[col];
#pragma unroll
    for (int mt = 0; mt < 2; ++mt)
#pragma unroll
      for (int r = 0; r < 4; ++r) {
        int row = rowbase + mt * 16 + (lane >> 4) * 4 + r;
        float v = acc[mt][nt][r] + bias;
        y[row * DD + col] = v;
        s[nt] += v; q2[nt] += v * v;
      }
  }
#pragma unroll
  for (int nt = 0; nt < 2; ++nt) {
    s[nt] += __shfl_xor(s[nt], 16);  s[nt] += __shfl_xor(s[nt], 32);
    q2[nt] += __shfl_xor(q2[nt], 16); q2[nt] += __shfl_xor(q2[nt], 32);
    if (lane < 16) {
      int col = colbase + nt * 16 + l15;
      atomicAdd(&sums[col], s[nt]);
      atomicAdd(&sumsq[col], q2[nt]);
    }
  }
}

// ---- BN apply + lrelu ----
__global__ __launch_bounds__(256) void k_bnapply(const float* __restrict__ y,
                                                 const float* __restrict__ sums,
                                                 const float* __restrict__ sumsq,
                                                 const float* __restrict__ gamma,
                                                 const float* __restrict__ beta,
                                                 float* __restrict__ out) {
  int idx = blockIdx.x * 256 + threadIdx.x;
  if (idx >= NTOK * DD) return;
  int c = idx & 511;
  float mean = sums[c] * (1.0f / 4096.0f);
  float var = sumsq[c] * (1.0f / 4096.0f) - mean * mean;
  float rstd = rsqrtf(var + 1e-5f);
  float v = (y[idx] - mean) * rstd * gamma[c] + beta[c];
  out[idx] = lrelu(v);
}

extern "C" void kernel_launch(void* const* d_in, const int* in_sizes, int n_in,
                              void* d_out, int out_size, void* d_ws, size_t ws_size,
                              hipStream_t stream) {
  const float* F   = (const float*)d_in[0];
  const float* W1  = (const float*)d_in[1];
  const float* b1  = (const float*)d_in[2];
  const float* W2  = (const float*)d_in[3];
  const float* b2  = (const float*)d_in[4];
  const float* W3  = (const float*)d_in[5];
  const float* b3  = (const float*)d_in[6];
  const float* Wf  = (const float*)d_in[7];
  const float* bfv = (const float*)d_in[8];
  const float* gamma = (const float*)d_in[9];
  const float* beta  = (const float*)d_in[10];
  float* out = (float*)d_out;

  char* ws = (char*)d_ws;
  unsigned short* XP  = (unsigned short*)(ws);                              // 8 MB panel [F | Msum]
  unsigned short* ACP = (unsigned short*)(ws + (8u << 20));                 // 8 MB panel
  unsigned short* W1P = (unsigned short*)(ws + (16u << 20));                // 1 MB
  unsigned short* W2P = (unsigned short*)(ws + (17u << 20));                // 0.5 MB (32-frag)
  unsigned short* W3P = (unsigned short*)(ws + (17u << 20) + (512u << 10)); // 0.5 MB (32-frag)
  unsigned short* WfP = (unsigned short*)(ws + (18u << 20));                // 1 MB
  float* y            = (float*)(ws + (19u << 20));                         // 8 MB
  float* sums         = (float*)(ws + (27u << 20));                         // 2 KB
  float* sumsq        = sums + 512;                                         // 2 KB

  k_prep<<<14337, 256, 0, stream>>>(F, W1, W2, W3, Wf, XP, W1P, W2P, W3P, WfP, sums);
  k_gemm_ac<<<dim3(64, 4), 512, 0, stream>>>(XP, W1P, ACP);
  k_relation<<<512, 1024, 0, stream>>>(ACP, W2P, W3P, b1, b2, b3, XP);
  k_fusion<<<dim3(64, 4), 512, 0, stream>>>(XP, WfP, bfv, y, sums, sumsq);
  k_bnapply<<<(NTOK * DD + 255) / 256, 256, 0, stream>>>(y, sums, sumsq, gamma, beta, out);
}

// Round 8
// 124.870 us; speedup vs baseline: 1.0144x; 1.0144x over previous
//
#include <hip/hip_runtime.h>

using f32x4  = __attribute__((ext_vector_type(4))) float;
using f32x16 = __attribute__((ext_vector_type(16))) float;
using bf16x8 = __attribute__((ext_vector_type(8))) __bf16;

static constexpr int DD = 512;
static constexpr int NTOK = 4096;  // B*V

__device__ __forceinline__ float bf2f(unsigned short u) {
  unsigned int v = ((unsigned int)u) << 16;
  return __builtin_bit_cast(float, v);
}
__device__ __forceinline__ float bflo(unsigned int u) {
  return __builtin_bit_cast(float, u << 16);
}
__device__ __forceinline__ float bfhi(unsigned int u) {
  return __builtin_bit_cast(float, u & 0xffff0000u);
}
__device__ __forceinline__ unsigned short f2bf(float f) {
  unsigned int u = __builtin_bit_cast(unsigned int, f);
  unsigned int r = u + 0x7fffu + ((u >> 16) & 1u);
  return (unsigned short)(r >> 16);
}
__device__ __forceinline__ float lrelu(float v) { return v >= 0.f ? v : 0.2f * v; }

// 16-wide fragment-panel (for gemm_ac/fusion, 16x16x32 MFMA):
//   off = (tile16*KS + ks)*512 + ((k>>3)&3)*128 + (row&15)*8 + (k&7)
// 32-wide fragment-panel (relation, 32x32x16 MFMA), lane = ((k>>3)&1)*32+row31:
//   off = frag*512 + ((k>>3)&1)*256 + (row&31)*8 + (k&7)

// ---- k_prep: all layout transforms + BN accumulator zeroing, one dispatch ----
__global__ __launch_bounds__(256) void k_prep(const float* __restrict__ F,
                                              const float* __restrict__ W1,
                                              const float* __restrict__ W2,
                                              const float* __restrict__ W3,
                                              const float* __restrict__ Wf,
                                              unsigned short* __restrict__ XP,
                                              unsigned short* __restrict__ W1P,
                                              unsigned short* __restrict__ W2P,
                                              unsigned short* __restrict__ W3P,
                                              unsigned short* __restrict__ WfP,
                                              float* __restrict__ sums) {
  const int bid = blockIdx.x, tid = threadIdx.x;
  if (bid < 8192) {                       // F -> XP (16-panel layout, ks 0..15 of 32)
    int idx = (bid << 8) + tid;           // 4096*512
    int t = idx >> 9, c = idx & 511;
    XP[((t >> 4) * 32 + (c >> 5)) * 512 + ((c >> 3) & 3) * 128 + (t & 15) * 8 + (c & 7)] = f2bf(F[idx]);
  } else if (bid < 10240) {               // W1 (1024,512) -> W1P 16-frag order (K=512, N=1024 combined)
    int idx = ((bid - 8192) << 8) + tid;  // 512*1024
    int k = idx >> 10, n = idx & 1023;
    float v = W1[(n < 512 ? k : 512 + k) * 512 + (n & 511)];
    W1P[((n >> 4) * 16 + (k >> 5)) * 512 + ((k >> 3) & 3) * 128 + (n & 15) * 8 + (k & 7)] = f2bf(v);
  } else if (bid < 11264) {               // W2 (512,512) -> W2P 32-frag fg-major
    int idx = ((bid - 10240) << 8) + tid;
    int k = idx >> 9, n = idx & 511;
    int off = (((n >> 6) * 32 + (k >> 4)) * 2 + ((n >> 5) & 1)) * 512 +
              ((k >> 3) & 1) * 256 + (n & 31) * 8 + (k & 7);
    W2P[off] = f2bf(W2[idx]);
  } else if (bid < 12288) {               // W3 -> 32-frag fg-major
    int idx = ((bid - 11264) << 8) + tid;
    int k = idx >> 9, n = idx & 511;
    int off = (((n >> 6) * 32 + (k >> 4)) * 2 + ((n >> 5) & 1)) * 512 +
              ((k >> 3) & 1) * 256 + (n & 31) * 8 + (k & 7);
    W3P[off] = f2bf(W3[idx]);
  } else if (bid < 14336) {               // Wf (1024,512) -> WfP 16-frag (K=1024)
    int idx = ((bid - 12288) << 8) + tid;
    int k = idx >> 9, n = idx & 511;
    WfP[((n >> 4) * 32 + (k >> 5)) * 512 + ((k >> 3) & 3) * 128 + (n & 15) * 8 + (k & 7)] = f2bf(Wf[idx]);
  } else {                                // zero sums+sumsq (1024 floats)
    reinterpret_cast<float4*>(sums)[tid] = float4{0.f, 0.f, 0.f, 0.f};
  }
}

// ---- GEMM1: ACP = [F@W1a | F@W1b] in 16-panel layout. grid (64,4), 512 thr ----
__global__ __launch_bounds__(512) void k_gemm_ac(const unsigned short* __restrict__ XP,
                                                 const unsigned short* __restrict__ W1P,
                                                 unsigned short* __restrict__ ACP) {
  const int tid = threadIdx.x, lane = tid & 63, wid = tid >> 6;
  const int wm = wid >> 2, wn = wid & 3;
  const int l15 = lane & 15;
  const int bx = blockIdx.x, by = blockIdx.y;

  f32x4 acc[2][4];
#pragma unroll
  for (int mt = 0; mt < 2; ++mt)
#pragma unroll
    for (int nt = 0; nt < 4; ++nt) acc[mt][nt] = f32x4{0.f, 0.f, 0.f, 0.f};

  bf16x8 ca[2], cb[4], na[2], nb[4];
  auto ldA = [&](bf16x8 (&d)[2], int ks) {
#pragma unroll
    for (int mt = 0; mt < 2; ++mt)
      d[mt] = *reinterpret_cast<const bf16x8*>(XP + (((bx * 4 + wm * 2 + mt) * 32 + ks) << 9) + lane * 8);
  };
  auto ldB = [&](bf16x8 (&d)[4], int ks) {
#pragma unroll
    for (int nt = 0; nt < 4; ++nt)
      d[nt] = *reinterpret_cast<const bf16x8*>(W1P + ((((by * 16 + wn * 4 + nt) * 16) + ks) << 9) + lane * 8);
  };

  ldA(ca, 0); ldB(cb, 0);
  for (int ks = 0; ks < 16; ++ks) {
    int kn = (ks + 1) & 15;
    ldA(na, kn); ldB(nb, kn);
    __builtin_amdgcn_s_setprio(1);
#pragma unroll
    for (int mt = 0; mt < 2; ++mt)
#pragma unroll
      for (int nt = 0; nt < 4; ++nt)
        acc[mt][nt] = __builtin_amdgcn_mfma_f32_16x16x32_bf16(ca[mt], cb[nt], acc[mt][nt], 0, 0, 0);
    __builtin_amdgcn_s_setprio(0);
#pragma unroll
    for (int q = 0; q < 2; ++q) ca[q] = na[q];
#pragma unroll
    for (int q = 0; q < 4; ++q) cb[q] = nb[q];
  }
#pragma unroll
  for (int mt = 0; mt < 2; ++mt)
#pragma unroll
    for (int nt = 0; nt < 4; ++nt) {
      int col = by * 256 + wn * 64 + nt * 16 + l15;
      int panel = bx * 4 + wm * 2 + mt;
#pragma unroll
      for (int r = 0; r < 4; ++r) {
        int rowi = (lane >> 4) * 4 + r;
        ACP[(panel * 32 + (col >> 5)) * 512 + ((col >> 3) & 3) * 128 + rowi * 8 + (col & 7)] = f2bf(acc[mt][nt][r]);
      }
    }
}

// ---- relation: block = (b, half) -> 8 tokens x 16 j = 128 relrows ----
// 32x32x16 MFMA. 1024 thr = 16 waves (4/SIMD), wave = fg(0..7; 64 feats) x rg(0..1; 64 relrows).
// Software-pipelined k-loop: W (global) 4-deep, H (LDS) 2-deep — every load is
// consumed >= 1.5 half-iters (~250-500 cyc) after issue, covering L2 latency.
__global__ __launch_bounds__(1024, 4) void k_relation(const unsigned short* __restrict__ ACP,
                                                      const unsigned short* __restrict__ W2P,
                                                      const unsigned short* __restrict__ W3P,
                                                      const float* __restrict__ b1,
                                                      const float* __restrict__ b2,
                                                      const float* __restrict__ b3,
                                                      unsigned short* __restrict__ XP) {
  __shared__ unsigned short lds[65536];  // 4 rtiles x 32 ks16 x 512 el = 128 KB
  char* ldsb = reinterpret_cast<char*>(lds);
  const int tid = threadIdx.x;
  const int b = blockIdx.x >> 1, half = blockIdx.x & 1;

  // ---- phase 0: h1 = lrelu(A_i + C_j + b1) -> LDS 32-frag panels ----
  {
    const int c8b = (tid >> 3) & 7;
    const int r = ((tid >> 6) << 3) | (tid & 7);   // relrow 0..127 = il*16 + j
    const int il = r >> 4, j = r & 15;
    const int rowA = half * 8 + il;
    const int rt = r >> 5, r31 = r & 31;
#pragma unroll
    for (int it = 0; it < 8; ++it) {
      const int c8 = c8b + it * 8;               // feat octet 0..63
      uint4 av = *reinterpret_cast<const uint4*>(ACP + ((b * 32 + (c8 >> 2)) << 9) + (c8 & 3) * 128 + rowA * 8);
      uint4 cv = *reinterpret_cast<const uint4*>(ACP + ((b * 32 + 16 + (c8 >> 2)) << 9) + (c8 & 3) * 128 + j * 8);
      float4 bv0 = *reinterpret_cast<const float4*>(b1 + c8 * 8);
      float4 bv1 = *reinterpret_cast<const float4*>(b1 + c8 * 8 + 4);
      unsigned int au[4] = {av.x, av.y, av.z, av.w};
      unsigned int cu[4] = {cv.x, cv.y, cv.z, cv.w};
      float bb[8] = {bv0.x, bv0.y, bv0.z, bv0.w, bv1.x, bv1.y, bv1.z, bv1.w};
      unsigned int ou[4];
#pragma unroll
      for (int q = 0; q < 4; ++q) {
        float v0 = lrelu(bflo(au[q]) + bflo(cu[q]) + bb[2 * q]);
        float v1 = lrelu(bfhi(au[q]) + bfhi(cu[q]) + bb[2 * q + 1]);
        ou[q] = ((unsigned int)f2bf(v1) << 16) | (unsigned int)f2bf(v0);
      }
      uint4 o; o.x = ou[0]; o.y = ou[1]; o.z = ou[2]; o.w = ou[3];
      *reinterpret_cast<uint4*>(ldsb + (rt * 32 + (c8 >> 1)) * 1024 + (c8 & 1) * 512 + r31 * 16) = o;
    }
  }
  __syncthreads();

  const int lane = tid & 63, wid = tid >> 6;
  const int r31 = lane & 31, h = lane >> 5;
  const int fg = wid >> 1;     // feature group: feats fg*64..+63 (2 m-tiles of 32)
  const int rg = wid & 1;      // relrow group: rtiles rg*2, rg*2+1

  const unsigned short* w2base = W2P + (fg << 15) + lane * 8;   // fg*32*2*512
  const unsigned short* w3base = W3P + (fg << 15) + lane * 8;
  const unsigned short* lrd = lds + (rg * 2) * 32 * 512 + lane * 8;

  f32x16 acc[2][2];

  auto ldh0 = [&](int ks) { return *reinterpret_cast<const bf16x8*>(lrd + (ks & 31) * 512); };
  auto ldh1 = [&](int ks) { return *reinterpret_cast<const bf16x8*>(lrd + 32 * 512 + (ks & 31) * 512); };

#define MFMA4(A, B)                                                                     \
  __builtin_amdgcn_s_setprio(1);                                                        \
  acc[0][0] = __builtin_amdgcn_mfma_f32_32x32x16_bf16(A##0, B##0, acc[0][0], 0, 0, 0);  \
  acc[0][1] = __builtin_amdgcn_mfma_f32_32x32x16_bf16(A##0, B##1, acc[0][1], 0, 0, 0);  \
  acc[1][0] = __builtin_amdgcn_mfma_f32_32x32x16_bf16(A##1, B##0, acc[1][0], 0, 0, 0);  \
  acc[1][1] = __builtin_amdgcn_mfma_f32_32x32x16_bf16(A##1, B##1, acc[1][1], 0, 0, 0);  \
  __builtin_amdgcn_s_setprio(0);

  auto layer = [&](const unsigned short* __restrict__ wb) {
#pragma unroll
    for (int mt = 0; mt < 2; ++mt)
#pragma unroll
      for (int nt = 0; nt < 2; ++nt)
#pragma unroll
        for (int e = 0; e < 16; ++e) acc[mt][nt][e] = 0.f;

    const unsigned short* wp = wb;   // points at W[k4+4] block each body; advances 4096 el/body
    bf16x8 a0_0, a0_1, a1_0, a1_1, a2_0, a2_1, a3_0, a3_1, bA0, bA1, bB0, bB1;
    a0_0 = *reinterpret_cast<const bf16x8*>(wp + 0);
    a0_1 = *reinterpret_cast<const bf16x8*>(wp + 512);
    a1_0 = *reinterpret_cast<const bf16x8*>(wp + 1024);
    a1_1 = *reinterpret_cast<const bf16x8*>(wp + 1536);
    a2_0 = *reinterpret_cast<const bf16x8*>(wp + 2048);
    a2_1 = *reinterpret_cast<const bf16x8*>(wp + 2560);
    a3_0 = *reinterpret_cast<const bf16x8*>(wp + 3072);
    a3_1 = *reinterpret_cast<const bf16x8*>(wp + 3584);
    wp += 4096;
    bA0 = ldh0(0); bA1 = ldh1(0);

#pragma unroll 1
    for (int k4 = 0; k4 < 32; k4 += 4) {
      // h0: consume a0 (W[k4]) + bA (H[k4]); refill a0 <- W[k4+4], bB <- H[k4+1]
      bB0 = ldh0(k4 + 1); bB1 = ldh1(k4 + 1);
      MFMA4(a0_, bA)
      a0_0 = *reinterpret_cast<const bf16x8*>(wp + 0);
      a0_1 = *reinterpret_cast<const bf16x8*>(wp + 512);
      bA0 = ldh0(k4 + 2); bA1 = ldh1(k4 + 2);
      // h1
      MFMA4(a1_, bB)
      a1_0 = *reinterpret_cast<const bf16x8*>(wp + 1024);
      a1_1 = *reinterpret_cast<const bf16x8*>(wp + 1536);
      bB0 = ldh0(k4 + 3); bB1 = ldh1(k4 + 3);
      // h2
      MFMA4(a2_, bA)
      a2_0 = *reinterpret_cast<const bf16x8*>(wp + 2048);
      a2_1 = *reinterpret_cast<const bf16x8*>(wp + 2560);
      bA0 = ldh0(k4 + 4); bA1 = ldh1(k4 + 4);
      // h3
      MFMA4(a3_, bB)
      a3_0 = *reinterpret_cast<const bf16x8*>(wp + 3072);
      a3_1 = *reinterpret_cast<const bf16x8*>(wp + 3584);
      wp += 4096;
    }
  };
#undef MFMA4

  // store lrelu(acc + bias) into LDS h-panels (uint2 per 4-reg group)
  auto store_h = [&](const float* __restrict__ bias) {
#pragma unroll
    for (int mt = 0; mt < 2; ++mt)
#pragma unroll
      for (int g = 0; g < 4; ++g) {
        float4 bv = *reinterpret_cast<const float4*>(bias + fg * 64 + mt * 32 + g * 8 + h * 4);
        const int ks16 = fg * 4 + mt * 2 + (g >> 1);
        const int kh = g & 1;
#pragma unroll
        for (int nt = 0; nt < 2; ++nt) {
          unsigned int w0 = f2bf(lrelu(acc[mt][nt][4 * g + 0] + bv.x));
          unsigned int w1 = f2bf(lrelu(acc[mt][nt][4 * g + 1] + bv.y));
          unsigned int w2 = f2bf(lrelu(acc[mt][nt][4 * g + 2] + bv.z));
          unsigned int w3 = f2bf(lrelu(acc[mt][nt][4 * g + 3] + bv.w));
          uint2 val; val.x = (w1 << 16) | w0; val.y = (w3 << 16) | w2;
          *reinterpret_cast<uint2*>(ldsb + ((rg * 2 + nt) * 32 + ks16) * 1024 + kh * 512 + r31 * 16 + h * 8) = val;
        }
      }
  };

  layer(w2base);
  __syncthreads();           // all waves done reading h1
  store_h(b2);
  __syncthreads();
  layer(w3base);
  __syncthreads();           // all waves done reading h2
  store_h(b3);
  __syncthreads();

  // ---- j-sum: Msum[token][feat] = sum_j h3[il*16+j][feat], waves 0..7 ----
  if (wid < 8) {
    const int t = wid;             // token 0..7 within block
    const int o = lane;            // feat octet 0..63
    const char* base = ldsb + ((t >> 1) * 32 + (o >> 1)) * 1024 + (o & 1) * 512 + (t & 1) * 256;
    float s[8] = {0.f, 0.f, 0.f, 0.f, 0.f, 0.f, 0.f, 0.f};
#pragma unroll
    for (int it = 0; it < 16; ++it) {
      int j = (it + o) & 15;       // rotate to spread banks
      uint4 v = *reinterpret_cast<const uint4*>(base + j * 16);
      s[0] += bflo(v.x); s[1] += bfhi(v.x);
      s[2] += bflo(v.y); s[3] += bfhi(v.y);
      s[4] += bflo(v.z); s[5] += bfhi(v.z);
      s[6] += bflo(v.w); s[7] += bfhi(v.w);
    }
    uint4 o4;
    o4.x = ((unsigned int)f2bf(s[1]) << 16) | f2bf(s[0]);
    o4.y = ((unsigned int)f2bf(s[3]) << 16) | f2bf(s[2]);
    o4.z = ((unsigned int)f2bf(s[5]) << 16) | f2bf(s[4]);
    o4.w = ((unsigned int)f2bf(s[7]) << 16) | f2bf(s[6]);
    int tg15 = half * 8 + t;       // token within 16-token panel (panel = b)
    *reinterpret_cast<uint4*>(XP + ((b * 32 + 16 + (o >> 2)) << 9) + (o & 3) * 128 + tg15 * 8) = o4;
  }
}

// ---- fusion GEMM + BN partial stats. grid (64,4), 512 thr ----
__global__ __launch_bounds__(512) void k_fusion(const unsigned short* __restrict__ XP,
                                                const unsigned short* __restrict__ WfP,
                                                const float* __restrict__ bfv,
                                                float* __restrict__ y,
                                                float* __restrict__ sums,
                                                float* __restrict__ sumsq) {
  const int tid = threadIdx.x, lane = tid & 63, wid = tid >> 6;
  const int wm = wid >> 2, wn = wid & 3;
  const int l15 = lane & 15;
  const int bx = blockIdx.x, by = blockIdx.y;
  const int rowbase = bx * 64 + wm * 32;
  const int colbase = by * 128 + wn * 32;

  f32x4 acc[2][2];
#pragma unroll
  for (int mt = 0; mt < 2; ++mt)
#pragma unroll
    for (int nt = 0; nt < 2; ++nt) acc[mt][nt] = f32x4{0.f, 0.f, 0.f, 0.f};

  bf16x8 ca[2], cb[2], na[2], nb[2];
  auto ldA = [&](bf16x8 (&d)[2], int ks) {
#pragma unroll
    for (int mt = 0; mt < 2; ++mt)
      d[mt] = *reinterpret_cast<const bf16x8*>(XP + (((bx * 4 + wm * 2 + mt) * 32 + ks) << 9) + lane * 8);
  };
  auto ldB = [&](bf16x8 (&d)[2], int ks) {
#pragma unroll
    for (int nt = 0; nt < 2; ++nt)
      d[nt] = *reinterpret_cast<const bf16x8*>(WfP + (((by * 8 + wn * 2 + nt) * 32 + ks) << 9) + lane * 8);
  };

  ldA(ca, 0); ldB(cb, 0);
  for (int ks = 0; ks < 32; ++ks) {
    int kn = (ks + 1) & 31;
    ldA(na, kn); ldB(nb, kn);
    __builtin_amdgcn_s_setprio(1);
#pragma unroll
    for (int mt = 0; mt < 2; ++mt)
#pragma unroll
      for (int nt = 0; nt < 2; ++nt)
        acc[mt][nt] = __builtin_amdgcn_mfma_f32_16x16x32_bf16(ca[mt], cb[nt], acc[mt][nt], 0, 0, 0);
    __builtin_amdgcn_s_setprio(0);
#pragma unroll
    for (int q = 0; q < 2; ++q) { ca[q] = na[q]; cb[q] = nb[q]; }
  }

  float s[2] = {0.f, 0.f}, q2[2] = {0.f, 0.f};
#pragma unroll
  for (int nt = 0; nt < 2; ++nt) {
    int col = colbase + nt * 16 + l15;
    float bias = bfv[col];
#pragma unroll
    for (int mt = 0; mt < 2; ++mt)
#pragma unroll
      for (int r = 0; r < 4; ++r) {
        int row = rowbase + mt * 16 + (lane >> 4) * 4 + r;
        float v = acc[mt][nt][r] + bias;
        y[row * DD + col] = v;
        s[nt] += v; q2[nt] += v * v;
      }
  }
#pragma unroll
  for (int nt = 0; nt < 2; ++nt) {
    s[nt] += __shfl_xor(s[nt], 16);  s[nt] += __shfl_xor(s[nt], 32);
    q2[nt] += __shfl_xor(q2[nt], 16); q2[nt] += __shfl_xor(q2[nt], 32);
    if (lane < 16) {
      int col = colbase + nt * 16 + l15;
      atomicAdd(&sums[col], s[nt]);
      atomicAdd(&sumsq[col], q2[nt]);
    }
  }
}

// ---- BN apply + lrelu ----
__global__ __launch_bounds__(256) void k_bnapply(const float* __restrict__ y,
                                                 const float* __restrict__ sums,
                                                 const float* __restrict__ sumsq,
                                                 const float* __restrict__ gamma,
                                                 const float* __restrict__ beta,
                                                 float* __restrict__ out) {
  int idx = blockIdx.x * 256 + threadIdx.x;
  if (idx >= NTOK * DD) return;
  int c = idx & 511;
  float mean = sums[c] * (1.0f / 4096.0f);
  float var = sumsq[c] * (1.0f / 4096.0f) - mean * mean;
  float rstd = rsqrtf(var + 1e-5f);
  float v = (y[idx] - mean) * rstd * gamma[c] + beta[c];
  out[idx] = lrelu(v);
}

extern "C" void kernel_launch(void* const* d_in, const int* in_sizes, int n_in,
                              void* d_out, int out_size, void* d_ws, size_t ws_size,
                              hipStream_t stream) {
  const float* F   = (const float*)d_in[0];
  const float* W1  = (const float*)d_in[1];
  const float* b1  = (const float*)d_in[2];
  const float* W2  = (const float*)d_in[3];
  const float* b2  = (const float*)d_in[4];
  const float* W3  = (const float*)d_in[5];
  const float* b3  = (const float*)d_in[6];
  const float* Wf  = (const float*)d_in[7];
  const float* bfv = (const float*)d_in[8];
  const float* gamma = (const float*)d_in[9];
  const float* beta  = (const float*)d_in[10];
  float* out = (float*)d_out;

  char* ws = (char*)d_ws;
  unsigned short* XP  = (unsigned short*)(ws);                              // 8 MB panel [F | Msum]
  unsigned short* ACP = (unsigned short*)(ws + (8u << 20));                 // 8 MB panel
  unsigned short* W1P = (unsigned short*)(ws + (16u << 20));                // 1 MB
  unsigned short* W2P = (unsigned short*)(ws + (17u << 20));                // 0.5 MB (32-frag)
  unsigned short* W3P = (unsigned short*)(ws + (17u << 20) + (512u << 10)); // 0.5 MB (32-frag)
  unsigned short* WfP = (unsigned short*)(ws + (18u << 20));                // 1 MB
  float* y            = (float*)(ws + (19u << 20));                         // 8 MB
  float* sums         = (float*)(ws + (27u << 20));                         // 2 KB
  float* sumsq        = sums + 512;                                         // 2 KB

  k_prep<<<14337, 256, 0, stream>>>(F, W1, W2, W3, Wf, XP, W1P, W2P, W3P, WfP, sums);
  k_gemm_ac<<<dim3(64, 4), 512, 0, stream>>>(XP, W1P, ACP);
  k_relation<<<512, 1024, 0, stream>>>(ACP, W2P, W3P, b1, b2, b3, XP);
  k_fusion<<<dim3(64, 4), 512, 0, stream>>>(XP, WfP, bfv, y, sums, sumsq);
  k_bnapply<<<(NTOK * DD + 255) / 256, 256, 0, stream>>>(y, sums, sumsq, gamma, beta, out);
}